// Round 4
// baseline (356.133 us; speedup 1.0000x reference)
//
#include <hip/hip_runtime.h>
#include <hip/hip_bf16.h>
#include <math.h>

#define BATCH   512
#define IN_DIM  4096
#define HID_DIM 8192
#define OUT_DIM 1024
#define T_STEPS 10
#define LEAK    0.95f

typedef __attribute__((ext_vector_type(8))) short bf16x8;
typedef __attribute__((ext_vector_type(4))) float floatx4;

#define GLB_AS __attribute__((address_space(1)))
#define LDS_AS __attribute__((address_space(3)))

// async 16B/lane global->LDS: lds dest = wave-uniform base + lane*16
#define ASYNC_COPY16(gp, lp)                                                  \
    __builtin_amdgcn_global_load_lds((const GLB_AS unsigned int*)(gp),        \
                                     (LDS_AS unsigned int*)(lp), 16, 0, 0)

__device__ __forceinline__ unsigned short f2bf(float f) {
    unsigned int u = __float_as_uint(f);
    u += 0x7fffu + ((u >> 16) & 1u);   // RNE
    return (unsigned short)(u >> 16);
}

// ---------------------------------------------------------------------------
// r = bf16(sigmoid(x)), 4 elems/thread
// ---------------------------------------------------------------------------
__global__ __launch_bounds__(256) void rates_bf16(const float* __restrict__ x,
                                                  unsigned short* __restrict__ r, int n4) {
    int i = blockIdx.x * blockDim.x + threadIdx.x;
    if (i >= n4) return;
    float4 v = ((const float4*)x)[i];
    ushort4 o;
    o.x = f2bf(1.f / (1.f + __expf(-v.x)));
    o.y = f2bf(1.f / (1.f + __expf(-v.y)));
    o.z = f2bf(1.f / (1.f + __expf(-v.z)));
    o.w = f2bf(1.f / (1.f + __expf(-v.w)));
    ((ushort4*)r)[i] = o;
}

// ---------------------------------------------------------------------------
// transpose + convert: in fp32 [K][N] -> out bf16 [N][K]; 64x64 tiles
// ---------------------------------------------------------------------------
__global__ __launch_bounds__(256) void transpose_cvt(const float* __restrict__ in,
                                                     unsigned short* __restrict__ out,
                                                     int K, int N) {
    __shared__ float tile[64][65];
    const int nb = blockIdx.x * 64;
    const int kb = blockIdx.y * 64;
    const int t = threadIdx.x;
    const int tr = t >> 4;
    const int tc4 = (t & 15) * 4;
#pragma unroll
    for (int it = 0; it < 4; ++it) {
        int k = tr + 16 * it;
        float4 v = *(const float4*)&in[(size_t)(kb + k) * N + nb + tc4];
        tile[k][tc4 + 0] = v.x;
        tile[k][tc4 + 1] = v.y;
        tile[k][tc4 + 2] = v.z;
        tile[k][tc4 + 3] = v.w;
    }
    __syncthreads();
#pragma unroll
    for (int it = 0; it < 4; ++it) {
        int n = tr + 16 * it;
        ushort4 o;
        o.x = f2bf(tile[tc4 + 0][n]);
        o.y = f2bf(tile[tc4 + 1][n]);
        o.z = f2bf(tile[tc4 + 2][n]);
        o.w = f2bf(tile[tc4 + 3][n]);
        *(ushort4*)&out[(size_t)(nb + n) * K + kb + tc4] = o;
    }
}

// ---------------------------------------------------------------------------
// bf16 MFMA GEMM: C[M,N] = A[M,K] @ Bt[N,K]^T
// 128M x 64N tile, BK=64, 256 threads = 4 waves in 2x2 quadrants (64M x 32N).
// LDS stored as 16-row x 32-col chunks in FRAGMENT ORDER: within a chunk,
// lane l holds (row = l&15, k-group = l>>4) -> MFMA fragment reads are
// chunkbase + lane*16B = conflict-free (2-way, free per m136). The staging
// permutation only reorders lanes over the same 16x64B global footprint.
// SPLITK>1: blockIdx.z owns K/SPLITK slice, plain stores to C + z*M*N.
// ---------------------------------------------------------------------------
template <int SPLITK>
__global__ __launch_bounds__(256) void gemm_bf16(const unsigned short* __restrict__ A,
                                                 const unsigned short* __restrict__ Bt,
                                                 float* __restrict__ C,
                                                 int M, int N, int K) {
    __shared__ unsigned short As[128 * 64];   // 8 row-chunks x 2 k-chunks x 512
    __shared__ unsigned short Bs[64 * 64];    // 4 row-chunks x 2 k-chunks x 512

    const int tid = threadIdx.x;
    const int wave = tid >> 6;
    const int lane = tid & 63;
    const int wr = wave >> 1;      // M half (64 rows)
    const int wc = wave & 1;       // N half (32 cols)

    const int m0 = blockIdx.y * 128;
    const int n0 = blockIdx.x * 64;
    const int Kseg = K / SPLITK;
    const int kb = blockIdx.z * Kseg;

    // staging: lane -> (row = lane&15, kgroup = lane>>4) within each chunk
    const int ar = lane & 15;
    const int ac = (lane >> 4) * 8;
    const unsigned short* agp = A + (size_t)(m0 + wave * 32 + ar) * K + kb + ac;
    const unsigned short* bgp = Bt + (size_t)(n0 + wave * 16 + ar) * K + kb + ac;
    // wave w stages A chunks idx 4w..4w+3 (rc0/kc0, rc0/kc1, rc1/kc0, rc1/kc1)
    unsigned short* asl = &As[wave * 2048];
    unsigned short* bsl = &Bs[wave * 1024];

    const int fr = lane & 15;
    const int fq = lane >> 4;
    floatx4 acc[4][2] = {};

    for (int k0 = 0; k0 < Kseg; k0 += 64) {
        __syncthreads();
        ASYNC_COPY16(agp, asl);                                // rc+0, kc0
        ASYNC_COPY16(agp + 32, asl + 512);                     // rc+0, kc1
        ASYNC_COPY16(agp + (size_t)16 * K, asl + 1024);        // rc+1, kc0
        ASYNC_COPY16(agp + (size_t)16 * K + 32, asl + 1536);   // rc+1, kc1
        ASYNC_COPY16(bgp, bsl);                                // kc0
        ASYNC_COPY16(bgp + 32, bsl + 512);                     // kc1
        agp += 64;
        bgp += 64;
        __syncthreads();

#pragma unroll
        for (int kc = 0; kc < 2; ++kc) {
            bf16x8 af[4], bfr[2];
#pragma unroll
            for (int i = 0; i < 4; ++i)
                af[i] = *(const bf16x8*)&As[(wr * 8 + i * 2 + kc) * 512 + lane * 8];
#pragma unroll
            for (int j = 0; j < 2; ++j)
                bfr[j] = *(const bf16x8*)&Bs[(wc * 4 + j * 2 + kc) * 512 + lane * 8];
#pragma unroll
            for (int i = 0; i < 4; ++i)
#pragma unroll
                for (int j = 0; j < 2; ++j)
                    acc[i][j] = __builtin_amdgcn_mfma_f32_16x16x32_bf16(af[i], bfr[j], acc[i][j], 0, 0, 0);
        }
    }

    float* Cp = C + (size_t)blockIdx.z * M * N;
#pragma unroll
    for (int i = 0; i < 4; ++i) {
#pragma unroll
        for (int j = 0; j < 2; ++j) {
            int row = m0 + wr * 64 + i * 16 + fq * 4;
            int col = n0 + wc * 32 + j * 16 + fr;
#pragma unroll
            for (int r = 0; r < 4; ++r)
                Cp[(size_t)(row + r) * N + col] = acc[i][j][r];
        }
    }
}

// ---------------------------------------------------------------------------
// First-spike scan (exact structural reduction: REFRACT=1 & t=spike_count =>
// each neuron spikes at most once ever; adaptation unreachable). Finds the
// batch index of the single spike (or -1). NPART partial buffers are summed.
// ---------------------------------------------------------------------------
template <int NPART>
__global__ __launch_bounds__(256) void first_spike(const float* __restrict__ cur,
                                                   int* __restrict__ b_fire, int n) {
    int j = blockIdx.x * blockDim.x + threadIdx.x;
    float v = 0.f;
    bool fired = false;
    int bf = -1;
    for (int b = 0; b < BATCH; ++b) {
        float c = 0.f;
#pragma unroll
        for (int z = 0; z < NPART; ++z)
            c += cur[(size_t)z * BATCH * n + (size_t)b * n + j];
#pragma unroll
        for (int t = 0; t < T_STEPS; ++t) {
            v = v * LEAK + c;
            if (!fired && v >= 1.0f) { fired = true; bf = b; }
        }
        if (__all((int)fired)) break;
    }
    b_fire[j] = bf;
}

// rate[b][j] = (b_fire[j]==b) ? 0.1 : 0, bf16, 4 elems/thread, wide grid
__global__ __launch_bounds__(256) void write_rate_bf16(const int* __restrict__ b_fire,
                                                       unsigned short* __restrict__ rate) {
    int gid = blockIdx.x * blockDim.x + threadIdx.x;       // over B*HID/4
    int b = gid >> 11;                                     // HID/4 = 2048
    int j = (gid & 2047) << 2;
    int4 bf = *(const int4*)&b_fire[j];
    const unsigned short ot = f2bf(0.1f);
    ushort4 o;
    o.x = (bf.x == b) ? ot : 0;
    o.y = (bf.y == b) ? ot : 0;
    o.z = (bf.z == b) ? ot : 0;
    o.w = (bf.w == b) ? ot : 0;
    *(ushort4*)&rate[(size_t)b * HID_DIM + j] = o;
}

// out[b][k] = (b_fire[k]==b) ? 0.1f : 0, fp32, 4 elems/thread
__global__ __launch_bounds__(256) void write_out_f32(const int* __restrict__ b_fire,
                                                     float* __restrict__ out) {
    int gid = blockIdx.x * blockDim.x + threadIdx.x;       // over B*OUT/4
    int b = gid >> 8;                                      // OUT/4 = 256
    int k = (gid & 255) << 2;
    int4 bf = *(const int4*)&b_fire[k];
    float4 o;
    o.x = (bf.x == b) ? 0.1f : 0.f;
    o.y = (bf.y == b) ? 0.1f : 0.f;
    o.z = (bf.z == b) ? 0.1f : 0.f;
    o.w = (bf.w == b) ? 0.1f : 0.f;
    *(float4*)&out[(size_t)b * OUT_DIM + k] = o;
}

// ---------------------------------------------------------------------------
extern "C" void kernel_launch(void* const* d_in, const int* in_sizes, int n_in,
                              void* d_out, int out_size, void* d_ws, size_t ws_size,
                              hipStream_t stream) {
    const float* x    = (const float*)d_in[0];  // [512, 4096]
    const float* W_ih = (const float*)d_in[1];  // [4096, 8192]
    const float* W_ho = (const float*)d_in[2];  // [8192, 1024]
    float* out = (float*)d_out;                 // [512, 1024] fp32

    char* base = (char*)d_ws;
    float*          cur_h   = (float*)(base + 0);                  // 16.8 MB; later cur_o parts (8 x 2 MB)
    unsigned short* r_bf    = (unsigned short*)(base + 16777216);  //  4.2 MB
    unsigned short* h_rate  = (unsigned short*)(base + 20971520);  //  8.4 MB
    int*            bfire_h = (int*)(base + 29360128);             //  32 KB
    int*            bfire_o = (int*)(base + 29392896);             //   4 KB
    unsigned short* Wt      = (unsigned short*)(base + 31457280);  // 67.1 MB (Wih^T, then Who^T)
    float*          cur_o   = cur_h;  // overlay: cur_h consumed by first_spike before GEMM2

    // 1) input rates -> bf16 [512][4096]
    int n4 = BATCH * IN_DIM / 4;
    rates_bf16<<<n4 / 256, 256, 0, stream>>>(x, r_bf, n4);

    // 2) Wt = bf16(W_ih^T)  [8192][4096]
    transpose_cvt<<<dim3(HID_DIM / 64, IN_DIM / 64), 256, 0, stream>>>(W_ih, Wt, IN_DIM, HID_DIM);

    // 3) cur_h = r_bf @ Wt^T  [512][8192]; 128x64 tiles -> 512 blocks, 2/CU
    gemm_bf16<1><<<dim3(HID_DIM / 64, BATCH / 128, 1), 256, 0, stream>>>(
        r_bf, Wt, cur_h, BATCH, HID_DIM, IN_DIM);

    // 4) hidden first-spike scan -> bfire_h [8192]
    first_spike<1><<<HID_DIM / 256, 256, 0, stream>>>(cur_h, bfire_h, HID_DIM);

    // 5) h_rate bf16 [512][8192] (wide, coalesced)
    write_rate_bf16<<<(BATCH * HID_DIM / 4) / 256, 256, 0, stream>>>(bfire_h, h_rate);

    // 6) Wt = bf16(W_ho^T)  [1024][8192] (overwrites)
    transpose_cvt<<<dim3(OUT_DIM / 64, HID_DIM / 64), 256, 0, stream>>>(W_ho, Wt, HID_DIM, OUT_DIM);

    // 7) cur_o partials: split-K=8, plain stores -> 8 x [512][1024]; 512 blocks
    gemm_bf16<8><<<dim3(OUT_DIM / 64, BATCH / 128, 8), 256, 0, stream>>>(
        h_rate, Wt, cur_o, BATCH, OUT_DIM, HID_DIM);

    // 8) output first-spike scan (sums 8 partials) -> bfire_o [1024]
    first_spike<8><<<OUT_DIM / 256, 256, 0, stream>>>(cur_o, bfire_o, OUT_DIM);

    // 9) d_out [512][1024] fp32 (wide, coalesced)
    write_out_f32<<<(BATCH * OUT_DIM / 4) / 256, 256, 0, stream>>>(bfire_o, out);
}

// Round 5
// 355.676 us; speedup vs baseline: 1.0013x; 1.0013x over previous
//
#include <hip/hip_runtime.h>
#include <hip/hip_bf16.h>
#include <math.h>

#define BATCH   512
#define IN_DIM  4096
#define HID_DIM 8192
#define OUT_DIM 1024
#define T_STEPS 10
#define LEAK    0.95f

typedef __attribute__((ext_vector_type(8))) short bf16x8;
typedef __attribute__((ext_vector_type(8))) unsigned short ushort8;
typedef __attribute__((ext_vector_type(4))) float floatx4;

#define GLB_AS __attribute__((address_space(1)))
#define LDS_AS __attribute__((address_space(3)))

// async 16B/lane global->LDS: lds dest = wave-uniform base + lane*16
#define ASYNC_COPY16(gp, lp)                                                  \
    __builtin_amdgcn_global_load_lds((const GLB_AS unsigned int*)(gp),        \
                                     (LDS_AS unsigned int*)(lp), 16, 0, 0)

__device__ __forceinline__ unsigned short f2bf(float f) {
    unsigned int u = __float_as_uint(f);
    u += 0x7fffu + ((u >> 16) & 1u);   // RNE
    return (unsigned short)(u >> 16);
}

// ---------------------------------------------------------------------------
// r = bf16(sigmoid(x)), 4 elems/thread
// ---------------------------------------------------------------------------
__global__ __launch_bounds__(256) void rates_bf16(const float* __restrict__ x,
                                                  unsigned short* __restrict__ r, int n4) {
    int i = blockIdx.x * blockDim.x + threadIdx.x;
    if (i >= n4) return;
    float4 v = ((const float4*)x)[i];
    ushort4 o;
    o.x = f2bf(1.f / (1.f + __expf(-v.x)));
    o.y = f2bf(1.f / (1.f + __expf(-v.y)));
    o.z = f2bf(1.f / (1.f + __expf(-v.z)));
    o.w = f2bf(1.f / (1.f + __expf(-v.w)));
    ((ushort4*)r)[i] = o;
}

// ---------------------------------------------------------------------------
// transpose + convert: in fp32 [K][N] -> out bf16 [N][K]; 64x64 tiles.
// Store phase: 16B ushort8 stores; LDS read banks (8a+b+j)%32 = 2-way (free).
// ---------------------------------------------------------------------------
__global__ __launch_bounds__(256) void transpose_cvt(const float* __restrict__ in,
                                                     unsigned short* __restrict__ out,
                                                     int K, int N) {
    __shared__ float tile[64][65];
    const int nb = blockIdx.x * 64;
    const int kb = blockIdx.y * 64;
    const int t = threadIdx.x;
    const int tr = t >> 4;
    const int tc4 = (t & 15) * 4;
#pragma unroll
    for (int it = 0; it < 4; ++it) {
        int k = tr + 16 * it;
        float4 v = *(const float4*)&in[(size_t)(kb + k) * N + nb + tc4];
        tile[k][tc4 + 0] = v.x;
        tile[k][tc4 + 1] = v.y;
        tile[k][tc4 + 2] = v.z;
        tile[k][tc4 + 3] = v.w;
    }
    __syncthreads();
    const int k8 = (t & 7) * 8;
    const int nr = t >> 3;          // 0..31
#pragma unroll
    for (int it = 0; it < 2; ++it) {
        int n = nr + 32 * it;
        ushort8 o;
#pragma unroll
        for (int j = 0; j < 8; ++j) o[j] = f2bf(tile[k8 + j][n]);
        *(ushort8*)&out[(size_t)(nb + n) * K + kb + k8] = o;
    }
}

// ---------------------------------------------------------------------------
// bf16 MFMA GEMM, double-buffered LDS: C[M,N] = A[M,K] @ Bt[N,K]^T
// 128M x 64N tile, BK=64, 256 threads = 4 waves in 2x2 quadrants (64M x 32N).
// LDS in fragment-order chunks (conflict-free, round-3 layout). One barrier
// per K-iter; async copies for iter k+1 issued right after the barrier so
// they overlap the whole MFMA phase (drained at the NEXT barrier's vmcnt(0)).
// SPLITK>1: blockIdx.z owns K/SPLITK slice, plain stores to C + z*M*N.
// ---------------------------------------------------------------------------
template <int SPLITK>
__global__ __launch_bounds__(256) void gemm_bf16(const unsigned short* __restrict__ A,
                                                 const unsigned short* __restrict__ Bt,
                                                 float* __restrict__ C,
                                                 int M, int N, int K) {
    __shared__ unsigned short As[2][128 * 64];   // 2 x 16 KB
    __shared__ unsigned short Bs[2][64 * 64];    // 2 x  8 KB

    const int tid = threadIdx.x;
    const int wave = tid >> 6;
    const int lane = tid & 63;
    const int wr = wave >> 1;      // M half (64 rows)
    const int wc = wave & 1;       // N half (32 cols)

    const int m0 = blockIdx.y * 128;
    const int n0 = blockIdx.x * 64;
    const int Kseg = K / SPLITK;
    const int kb = blockIdx.z * Kseg;

    // staging: lane -> (row = lane&15, kgroup = lane>>4) within each chunk
    const int ar = lane & 15;
    const int ac = (lane >> 4) * 8;
    const unsigned short* agp = A + (size_t)(m0 + wave * 32 + ar) * K + kb + ac;
    const unsigned short* bgp = Bt + (size_t)(n0 + wave * 16 + ar) * K + kb + ac;
    const int aoff = wave * 2048;   // wave's 4 A-chunks
    const int boff = wave * 1024;   // wave's 2 B-chunks

    const int fr = lane & 15;
    const int fq = lane >> 4;
    floatx4 acc[4][2] = {};

    // prologue: stage iter 0 into buffer 0
    {
        unsigned short* asl = &As[0][aoff];
        unsigned short* bsl = &Bs[0][boff];
        ASYNC_COPY16(agp, asl);
        ASYNC_COPY16(agp + 32, asl + 512);
        ASYNC_COPY16(agp + (size_t)16 * K, asl + 1024);
        ASYNC_COPY16(agp + (size_t)16 * K + 32, asl + 1536);
        ASYNC_COPY16(bgp, bsl);
        ASYNC_COPY16(bgp + 32, bsl + 512);
        agp += 64;
        bgp += 64;
    }

    int p = 0;
    for (int k0 = 0; k0 < Kseg; k0 += 64) {
        __syncthreads();   // drains copies into buf[p] (issued last iter) + prior ds_reads
        if (k0 + 64 < Kseg) {
            unsigned short* asl = &As[p ^ 1][aoff];
            unsigned short* bsl = &Bs[p ^ 1][boff];
            ASYNC_COPY16(agp, asl);
            ASYNC_COPY16(agp + 32, asl + 512);
            ASYNC_COPY16(agp + (size_t)16 * K, asl + 1024);
            ASYNC_COPY16(agp + (size_t)16 * K + 32, asl + 1536);
            ASYNC_COPY16(bgp, bsl);
            ASYNC_COPY16(bgp + 32, bsl + 512);
            agp += 64;
            bgp += 64;
        }
#pragma unroll
        for (int kc = 0; kc < 2; ++kc) {
            bf16x8 af[4], bfr[2];
#pragma unroll
            for (int i = 0; i < 4; ++i)
                af[i] = *(const bf16x8*)&As[p][(wr * 8 + i * 2 + kc) * 512 + lane * 8];
#pragma unroll
            for (int j = 0; j < 2; ++j)
                bfr[j] = *(const bf16x8*)&Bs[p][(wc * 4 + j * 2 + kc) * 512 + lane * 8];
#pragma unroll
            for (int i = 0; i < 4; ++i)
#pragma unroll
                for (int j = 0; j < 2; ++j)
                    acc[i][j] = __builtin_amdgcn_mfma_f32_16x16x32_bf16(af[i], bfr[j], acc[i][j], 0, 0, 0);
        }
        p ^= 1;
    }

    float* Cp = C + (size_t)blockIdx.z * M * N;
#pragma unroll
    for (int i = 0; i < 4; ++i) {
#pragma unroll
        for (int j = 0; j < 2; ++j) {
            int row = m0 + wr * 64 + i * 16 + fq * 4;
            int col = n0 + wc * 32 + j * 16 + fr;
#pragma unroll
            for (int r = 0; r < 4; ++r)
                Cp[(size_t)(row + r) * N + col] = acc[i][j][r];
        }
    }
}

// ---------------------------------------------------------------------------
// First-spike scan (exact structural reduction: REFRACT=1 & t=spike_count =>
// each neuron spikes at most once ever; adaptation unreachable). Finds the
// batch index of the single spike (or -1). NPART partial buffers are summed.
// ---------------------------------------------------------------------------
template <int NPART>
__global__ __launch_bounds__(256) void first_spike(const float* __restrict__ cur,
                                                   int* __restrict__ b_fire, int n) {
    int j = blockIdx.x * blockDim.x + threadIdx.x;
    float v = 0.f;
    bool fired = false;
    int bf = -1;
    for (int b = 0; b < BATCH; ++b) {
        float c = 0.f;
#pragma unroll
        for (int z = 0; z < NPART; ++z)
            c += cur[(size_t)z * BATCH * n + (size_t)b * n + j];
#pragma unroll
        for (int t = 0; t < T_STEPS; ++t) {
            v = v * LEAK + c;
            if (!fired && v >= 1.0f) { fired = true; bf = b; }
        }
        if (__all((int)fired)) break;
    }
    b_fire[j] = bf;
}

// rate[b][j] = (b_fire[j]==b) ? 0.1 : 0, bf16, 4 elems/thread, wide grid
__global__ __launch_bounds__(256) void write_rate_bf16(const int* __restrict__ b_fire,
                                                       unsigned short* __restrict__ rate) {
    int gid = blockIdx.x * blockDim.x + threadIdx.x;       // over B*HID/4
    int b = gid >> 11;                                     // HID/4 = 2048
    int j = (gid & 2047) << 2;
    int4 bf = *(const int4*)&b_fire[j];
    const unsigned short ot = f2bf(0.1f);
    ushort4 o;
    o.x = (bf.x == b) ? ot : 0;
    o.y = (bf.y == b) ? ot : 0;
    o.z = (bf.z == b) ? ot : 0;
    o.w = (bf.w == b) ? ot : 0;
    *(ushort4*)&rate[(size_t)b * HID_DIM + j] = o;
}

// out[b][k] = (b_fire[k]==b) ? 0.1f : 0, fp32, 4 elems/thread
__global__ __launch_bounds__(256) void write_out_f32(const int* __restrict__ b_fire,
                                                     float* __restrict__ out) {
    int gid = blockIdx.x * blockDim.x + threadIdx.x;       // over B*OUT/4
    int b = gid >> 8;                                      // OUT/4 = 256
    int k = (gid & 255) << 2;
    int4 bf = *(const int4*)&b_fire[k];
    float4 o;
    o.x = (bf.x == b) ? 0.1f : 0.f;
    o.y = (bf.y == b) ? 0.1f : 0.f;
    o.z = (bf.z == b) ? 0.1f : 0.f;
    o.w = (bf.w == b) ? 0.1f : 0.f;
    *(float4*)&out[(size_t)b * OUT_DIM + k] = o;
}

// ---------------------------------------------------------------------------
extern "C" void kernel_launch(void* const* d_in, const int* in_sizes, int n_in,
                              void* d_out, int out_size, void* d_ws, size_t ws_size,
                              hipStream_t stream) {
    const float* x    = (const float*)d_in[0];  // [512, 4096]
    const float* W_ih = (const float*)d_in[1];  // [4096, 8192]
    const float* W_ho = (const float*)d_in[2];  // [8192, 1024]
    float* out = (float*)d_out;                 // [512, 1024] fp32

    char* base = (char*)d_ws;
    float*          cur_h   = (float*)(base + 0);                  // 16.8 MB; later cur_o parts (8 x 2 MB)
    unsigned short* r_bf    = (unsigned short*)(base + 16777216);  //  4.2 MB
    unsigned short* h_rate  = (unsigned short*)(base + 20971520);  //  8.4 MB
    int*            bfire_h = (int*)(base + 29360128);             //  32 KB
    int*            bfire_o = (int*)(base + 29392896);             //   4 KB
    unsigned short* Wt      = (unsigned short*)(base + 31457280);  // 67.1 MB (Wih^T, then Who^T)
    float*          cur_o   = cur_h;  // overlay: cur_h consumed by first_spike before GEMM2

    // 1) input rates -> bf16 [512][4096]
    int n4 = BATCH * IN_DIM / 4;
    rates_bf16<<<n4 / 256, 256, 0, stream>>>(x, r_bf, n4);

    // 2) Wt = bf16(W_ih^T)  [8192][4096]
    transpose_cvt<<<dim3(HID_DIM / 64, IN_DIM / 64), 256, 0, stream>>>(W_ih, Wt, IN_DIM, HID_DIM);

    // 3) cur_h = r_bf @ Wt^T  [512][8192]; 128x64 tiles -> 512 blocks, 2/CU
    gemm_bf16<1><<<dim3(HID_DIM / 64, BATCH / 128, 1), 256, 0, stream>>>(
        r_bf, Wt, cur_h, BATCH, HID_DIM, IN_DIM);

    // 4) hidden first-spike scan -> bfire_h [8192]
    first_spike<1><<<HID_DIM / 256, 256, 0, stream>>>(cur_h, bfire_h, HID_DIM);

    // 5) h_rate bf16 [512][8192] (wide, coalesced)
    write_rate_bf16<<<(BATCH * HID_DIM / 4) / 256, 256, 0, stream>>>(bfire_h, h_rate);

    // 6) Wt = bf16(W_ho^T)  [1024][8192] (overwrites)
    transpose_cvt<<<dim3(OUT_DIM / 64, HID_DIM / 64), 256, 0, stream>>>(W_ho, Wt, HID_DIM, OUT_DIM);

    // 7) cur_o partials: split-K=8, plain stores -> 8 x [512][1024]; 512 blocks
    gemm_bf16<8><<<dim3(OUT_DIM / 64, BATCH / 128, 8), 256, 0, stream>>>(
        h_rate, Wt, cur_o, BATCH, OUT_DIM, HID_DIM);

    // 8) output first-spike scan (sums 8 partials) -> bfire_o [1024]
    first_spike<8><<<OUT_DIM / 256, 256, 0, stream>>>(cur_o, bfire_o, OUT_DIM);

    // 9) d_out [512][1024] fp32 (wide, coalesced)
    write_out_f32<<<(BATCH * OUT_DIM / 4) / 256, 256, 0, stream>>>(bfire_o, out);
}